// Round 7
// baseline (541.114 us; speedup 1.0000x reference)
//
#include <hip/hip_runtime.h>

// VQ argmin: x [16,64,64,64] NCHW fp32, codebook [1024,64] fp32.
// N = 65536 rows, D = 64, K = 1024. dist = ||e||^2 - 2 x.e (||x||^2 dropped).
//
// R7: R4/R6 both showed ~123 us of VALU busy-time vs the 54.6 us fmac floor.
// Attribution: the e-pointer is wave-uniform -> lives in SGPRs -> compiler
// materializes a VGPR address per global_load (~4-5 VALU each x 4096 loads).
// Fix: ONE opaque-zero VGPR folded into the pointer forces it into a VGPR
// pair; all 128 loads of a 2KB e-tile then use 13-bit immediate offsets with
// zero per-load VALU. x tile in f4-typed LDS (aligned ds_read_b128). e-norm
// pass folded in-block (R4 paid ~45 us of second-launch wall time).

typedef float f4 __attribute__((ext_vector_type(4)));

#define K_CODES 1024
#define D_DIM   64
#define HW      4096   // 64*64
#define ROWS    64     // rows per block

__global__ __launch_bounds__(256, 4) void vq_kernel(const float* __restrict__ x,
                                                    const float* __restrict__ cb,
                                                    int* __restrict__ out) {
    __shared__ f4    xs4[ROWS][17];   // row stride 272B: 16B-aligned, bank-balanced
    __shared__ float sEn[K_CODES];
    __shared__ float sd[256];
    __shared__ int   si[256];

    const int tid = threadIdx.x;
    const int r = tid & 63;
    const int quarter = __builtin_amdgcn_readfirstlane(tid >> 6);
    const int n0 = blockIdx.x * ROWS;
    const int b = n0 >> 12;
    const int hw0 = n0 & (HW - 1);

    // ---- in-block codebook norms: thread tid does codes tid, tid+256, ... ----
#pragma unroll
    for (int q = 0; q < 4; ++q) {
        const int k = q * 256 + tid;
        const f4* row = (const f4*)(cb + (size_t)k * D_DIM);
        float s = 0.f;
#pragma unroll
        for (int i = 0; i < D_DIM / 4; ++i) {
            f4 v = row[i];
            s = fmaf(v.x, v.x, s);
            s = fmaf(v.y, v.y, s);
            s = fmaf(v.z, v.z, s);
            s = fmaf(v.w, v.w, s);
        }
        sEn[k] = s;
    }

    // ---- stage x tile: wave q loads channels q*16..q*16+15 of all 64 rows ----
    {
        const float* g = x + ((size_t)b * D_DIM + quarter * 16) * HW + hw0 + r;
        float v[16];
#pragma unroll
        for (int i = 0; i < 16; ++i) v[i] = g[(size_t)i * HW];
#pragma unroll
        for (int j = 0; j < 4; ++j)
            xs4[r][quarter * 4 + j] = (f4){v[4*j], v[4*j+1], v[4*j+2], v[4*j+3]};
    }
    __syncthreads();

    // Opaque zero in a VGPR: forces the e-pointer into a VGPR pair so every
    // tile load is global_load_dwordx4 v, v[p:p+1], off offset:<imm>.
    int lz;
    asm("v_mov_b32 %0, 0" : "=v"(lz));

    const char* ep = (const char*)cb + (size_t)quarter * 65536 + lz;

    float best = __builtin_inff();
    int bestk = 0;

#pragma unroll 1
    for (int t = 0; t < 32; ++t) {                 // 32 tiles x 8 codes = 256
        const f4* __restrict__ ef = (const f4*)ep; // ef[c*16 + dc], offsets 0..2032B
        float acc0 = 0.f, acc1 = 0.f, acc2 = 0.f, acc3 = 0.f;
        float acc4 = 0.f, acc5 = 0.f, acc6 = 0.f, acc7 = 0.f;
#pragma unroll
        for (int dc = 0; dc < 16; ++dc) {
            const f4 x4 = xs4[r][dc];
            const f4 e0 = ef[0 * 16 + dc];
            const f4 e1 = ef[1 * 16 + dc];
            const f4 e2 = ef[2 * 16 + dc];
            const f4 e3 = ef[3 * 16 + dc];
            const f4 e4 = ef[4 * 16 + dc];
            const f4 e5 = ef[5 * 16 + dc];
            const f4 e6 = ef[6 * 16 + dc];
            const f4 e7 = ef[7 * 16 + dc];
            acc0 = fmaf(e0.x, x4.x, acc0); acc0 = fmaf(e0.y, x4.y, acc0);
            acc0 = fmaf(e0.z, x4.z, acc0); acc0 = fmaf(e0.w, x4.w, acc0);
            acc1 = fmaf(e1.x, x4.x, acc1); acc1 = fmaf(e1.y, x4.y, acc1);
            acc1 = fmaf(e1.z, x4.z, acc1); acc1 = fmaf(e1.w, x4.w, acc1);
            acc2 = fmaf(e2.x, x4.x, acc2); acc2 = fmaf(e2.y, x4.y, acc2);
            acc2 = fmaf(e2.z, x4.z, acc2); acc2 = fmaf(e2.w, x4.w, acc2);
            acc3 = fmaf(e3.x, x4.x, acc3); acc3 = fmaf(e3.y, x4.y, acc3);
            acc3 = fmaf(e3.z, x4.z, acc3); acc3 = fmaf(e3.w, x4.w, acc3);
            acc4 = fmaf(e4.x, x4.x, acc4); acc4 = fmaf(e4.y, x4.y, acc4);
            acc4 = fmaf(e4.z, x4.z, acc4); acc4 = fmaf(e4.w, x4.w, acc4);
            acc5 = fmaf(e5.x, x4.x, acc5); acc5 = fmaf(e5.y, x4.y, acc5);
            acc5 = fmaf(e5.z, x4.z, acc5); acc5 = fmaf(e5.w, x4.w, acc5);
            acc6 = fmaf(e6.x, x4.x, acc6); acc6 = fmaf(e6.y, x4.y, acc6);
            acc6 = fmaf(e6.z, x4.z, acc6); acc6 = fmaf(e6.w, x4.w, acc6);
            acc7 = fmaf(e7.x, x4.x, acc7); acc7 = fmaf(e7.y, x4.y, acc7);
            acc7 = fmaf(e7.z, x4.z, acc7); acc7 = fmaf(e7.w, x4.w, acc7);
        }
        const int kq = (quarter << 8) + (t << 3);
#define FIN(c) { const float dd = fmaf(-2.f, acc##c, sEn[kq + (c)]);         \
                 if (dd < best) { best = dd; bestk = kq + (c); } }
        FIN(0) FIN(1) FIN(2) FIN(3) FIN(4) FIN(5) FIN(6) FIN(7)
#undef FIN
        ep += 2048;
    }

    // combine 4 K-quarters per row; lower quarter (lower k) wins ties
    sd[tid] = best;
    si[tid] = bestk;
    __syncthreads();
    if (quarter == 0) {
#pragma unroll
        for (int q = 1; q < 4; ++q) {
            const float o = sd[q * 64 + r];
            const int  oi = si[q * 64 + r];
            if (o < best) { best = o; bestk = oi; }
        }
        out[n0 + r] = bestk;
    }
}

extern "C" void kernel_launch(void* const* d_in, const int* in_sizes, int n_in,
                              void* d_out, int out_size, void* d_ws, size_t ws_size,
                              hipStream_t stream) {
    const float* x  = (const float*)d_in[0];   // [16,64,64,64] fp32
    const float* cb = (const float*)d_in[1];   // [1024,64] fp32
    int*   out   = (int*)d_out;                // 65536 int32 indices

    vq_kernel<<<dim3(65536 / ROWS), dim3(256), 0, stream>>>(x, cb, out);
}

// Round 8
// 110.399 us; speedup vs baseline: 4.9014x; 4.9014x over previous
//
#include <hip/hip_runtime.h>

// VQ argmin via MFMA: x [16,64,64,64] NCHW fp32, codebook [1024,64] fp32.
// dist = ||e||^2 + (-2x).e  (||x||^2 dropped).  -2x.e computed as bf16 3-way
// split GEMM: x=-2x -> h+m+l (exact, 24 bits), e -> h+m+l; keep products with
// level-sum<=2 (hh, hm, mh, hl, mm, lh) -> dropped terms ~2^-26, below fp32
// rounding noise. 6 chained MFMAs per k-step into one fp32 accumulator.
//
// R8 rationale: R1-R7 all show the SAME ~124us "VALUBusy" time == the fmac
// count (gfx94x-formula counter, ~2x inflated); real fp32-vector floor ~62us,
// wall 163us was latency-stall. MFMA path floor ~25us.

typedef float f4 __attribute__((ext_vector_type(4)));
typedef short s8v __attribute__((ext_vector_type(8)));
typedef unsigned int u32;

#define D_DIM 64
#define HW    4096
#define ROWS  64
#define INF_  __builtin_inff()
#define MFMA(a,b,c) __builtin_amdgcn_mfma_f32_16x16x32_bf16(a,b,c,0,0,0)

__device__ __forceinline__ unsigned short bf_rne(float f) {
    u32 u = __builtin_bit_cast(u32, f);
    u32 r = u + 0x7fffu + ((u >> 16) & 1u);
    return (unsigned short)(r >> 16);
}
__device__ __forceinline__ float bf_to_f(unsigned short h) {
    u32 u = ((u32)h) << 16;
    return __builtin_bit_cast(float, u);
}
__device__ __forceinline__ void split3(float f, unsigned short& h,
                                       unsigned short& m, unsigned short& l) {
    h = bf_rne(f);
    float f1 = f - bf_to_f(h);
    m = bf_rne(f1);
    float f2 = f1 - bf_to_f(m);
    l = bf_rne(f2);
}
__device__ __forceinline__ s8v pack8(unsigned short a0, unsigned short a1,
                                     unsigned short a2, unsigned short a3,
                                     unsigned short a4, unsigned short a5,
                                     unsigned short a6, unsigned short a7) {
    uint4 u;
    u.x = a0 | ((u32)a1 << 16);
    u.y = a2 | ((u32)a3 << 16);
    u.z = a4 | ((u32)a5 << 16);
    u.w = a6 | ((u32)a7 << 16);
    return __builtin_bit_cast(s8v, u);
}

// ---- prep: split codebook into B-fragment-ordered bf16 h/m/l chunks + enorm.
// Chunk c = T*6 + s*3 + L (T=ntile 0..63, s=kstep, L=level): 64 lanes x 16B.
// lane: code = T*16 + (lane&15), ch = s*32 + (lane>>4)*8 + j  (B[k][n] layout:
// n = lane&15, k = (lane>>4)*8+j).  enorm (fp32, exact) at ws + 384KB.
__global__ __launch_bounds__(64) void prep_kernel(const float* __restrict__ cb,
                                                  char* __restrict__ wsb) {
    const int blk = blockIdx.x;
    const int lane = threadIdx.x;
    if (blk < 384) {
        const int T = blk / 6;
        const int rem = blk - T * 6;
        const int s = rem / 3;
        const int L = rem - s * 3;
        const int code = T * 16 + (lane & 15);
        const int ch0 = s * 32 + (lane >> 4) * 8;
        const float* src = cb + code * 64 + ch0;
        unsigned short o[8];
#pragma unroll
        for (int j = 0; j < 8; ++j) {
            unsigned short h, m2, l;
            split3(src[j], h, m2, l);
            o[j] = (L == 0) ? h : (L == 1) ? m2 : l;
        }
        uint4 w;
        w.x = o[0] | ((u32)o[1] << 16);
        w.y = o[2] | ((u32)o[3] << 16);
        w.z = o[4] | ((u32)o[5] << 16);
        w.w = o[6] | ((u32)o[7] << 16);
        *(uint4*)(wsb + (size_t)blk * 1024 + lane * 16) = w;
    } else {
        const int k = (blk - 384) * 64 + lane;
        const f4* row = (const f4*)(cb + (size_t)k * 64);
        float sacc = 0.f;
#pragma unroll
        for (int i = 0; i < 16; ++i) {
            f4 v = row[i];
            sacc = fmaf(v.x, v.x, sacc);
            sacc = fmaf(v.y, v.y, sacc);
            sacc = fmaf(v.z, v.z, sacc);
            sacc = fmaf(v.w, v.w, sacc);
        }
        ((float*)(wsb + 384 * 1024))[k] = sacc;
    }
}

// ---- main kernel macros (all state in NAMED vars: SROA-proof) ----
#define BUILD_AS(rs, s) {                                                    \
    const float* xr = (const float*)&xs4[(rs) * 16 + m_][0];                 \
    f4 va = *(const f4*)(xr + (s) * 32 + ko);                                \
    f4 vb = *(const f4*)(xr + (s) * 32 + ko + 4);                            \
    unsigned short h0,h1,h2,h3,h4,h5,h6,h7;                                  \
    unsigned short q0,q1,q2,q3,q4,q5,q6,q7;                                  \
    unsigned short l0,l1,l2,l3,l4,l5,l6,l7;                                  \
    split3(-2.f * va.x, h0, q0, l0); split3(-2.f * va.y, h1, q1, l1);        \
    split3(-2.f * va.z, h2, q2, l2); split3(-2.f * va.w, h3, q3, l3);        \
    split3(-2.f * vb.x, h4, q4, l4); split3(-2.f * vb.y, h5, q5, l5);        \
    split3(-2.f * vb.z, h6, q6, l6); split3(-2.f * vb.w, h7, q7, l7);        \
    Ah##rs##s = pack8(h0,h1,h2,h3,h4,h5,h6,h7);                              \
    Am##rs##s = pack8(q0,q1,q2,q3,q4,q5,q6,q7);                              \
    Al##rs##s = pack8(l0,l1,l2,l3,l4,l5,l6,l7);                              \
}

#define LOADB(S, P)                                                          \
    Bh0##S = *(const s8v*)((P) + 0);    Bm0##S = *(const s8v*)((P) + 1024);  \
    Bl0##S = *(const s8v*)((P) + 2048); Bh1##S = *(const s8v*)((P) + 3072);  \
    Bm1##S = *(const s8v*)((P) + 4096); Bl1##S = *(const s8v*)((P) + 5120);

// 24 MFMAs per k-step: pairs (h,h),(h,m),(m,h),(h,l),(m,m),(l,h), 4 rowstripes
// interleaved for 4 independent dependency chains.
#define MFMA_S(s, BH, BM, BL)                                                \
    acc0 = MFMA(Ah0##s, BH, acc0); acc1 = MFMA(Ah1##s, BH, acc1);            \
    acc2 = MFMA(Ah2##s, BH, acc2); acc3 = MFMA(Ah3##s, BH, acc3);            \
    acc0 = MFMA(Ah0##s, BM, acc0); acc1 = MFMA(Ah1##s, BM, acc1);            \
    acc2 = MFMA(Ah2##s, BM, acc2); acc3 = MFMA(Ah3##s, BM, acc3);            \
    acc0 = MFMA(Am0##s, BH, acc0); acc1 = MFMA(Am1##s, BH, acc1);            \
    acc2 = MFMA(Am2##s, BH, acc2); acc3 = MFMA(Am3##s, BH, acc3);            \
    acc0 = MFMA(Ah0##s, BL, acc0); acc1 = MFMA(Ah1##s, BL, acc1);            \
    acc2 = MFMA(Ah2##s, BL, acc2); acc3 = MFMA(Ah3##s, BL, acc3);            \
    acc0 = MFMA(Am0##s, BM, acc0); acc1 = MFMA(Am1##s, BM, acc1);            \
    acc2 = MFMA(Am2##s, BM, acc2); acc3 = MFMA(Am3##s, BM, acc3);            \
    acc0 = MFMA(Al0##s, BH, acc0); acc1 = MFMA(Al1##s, BH, acc1);            \
    acc2 = MFMA(Al2##s, BH, acc2); acc3 = MFMA(Al3##s, BH, acc3);

#define UPD(rs, i) {                                                         \
    float v = acc##rs[i] + en;                                               \
    bool p = (v < best_##rs##_##i);                                          \
    best_##rs##_##i = p ? v : best_##rs##_##i;                               \
    idx_##rs##_##i  = p ? kn : idx_##rs##_##i;                               \
}
#define EPILOG(TG) {                                                         \
    const int kn = (TG) * 16 + m_;                                           \
    const float en = sEn[kn];                                                \
    UPD(0,0) UPD(0,1) UPD(0,2) UPD(0,3)                                      \
    UPD(1,0) UPD(1,1) UPD(1,2) UPD(1,3)                                      \
    UPD(2,0) UPD(2,1) UPD(2,2) UPD(2,3)                                      \
    UPD(3,0) UPD(3,1) UPD(3,2) UPD(3,3)                                      \
    acc0 = (f4){0.f,0.f,0.f,0.f}; acc1 = (f4){0.f,0.f,0.f,0.f};              \
    acc2 = (f4){0.f,0.f,0.f,0.f}; acc3 = (f4){0.f,0.f,0.f,0.f};              \
}

#define DO_TILE(CUR, NXT, TG, NP) {                                          \
    LOADB(NXT, NP)                                                           \
    MFMA_S(0, Bh0##CUR, Bm0##CUR, Bl0##CUR)                                  \
    MFMA_S(1, Bh1##CUR, Bm1##CUR, Bl1##CUR)                                  \
    EPILOG(TG)                                                               \
}

#define BFLY1(rs, i, msk) {                                                  \
    float ov = __shfl_xor(best_##rs##_##i, msk);                             \
    int   oi = __shfl_xor(idx_##rs##_##i,  msk);                             \
    bool p = (ov < best_##rs##_##i) ||                                       \
             (ov == best_##rs##_##i && oi < idx_##rs##_##i);                 \
    best_##rs##_##i = p ? ov : best_##rs##_##i;                              \
    idx_##rs##_##i  = p ? oi : idx_##rs##_##i;                               \
}
#define BFLY_ALL(msk)                                                        \
    BFLY1(0,0,msk) BFLY1(0,1,msk) BFLY1(0,2,msk) BFLY1(0,3,msk)              \
    BFLY1(1,0,msk) BFLY1(1,1,msk) BFLY1(1,2,msk) BFLY1(1,3,msk)              \
    BFLY1(2,0,msk) BFLY1(2,1,msk) BFLY1(2,2,msk) BFLY1(2,3,msk)              \
    BFLY1(3,0,msk) BFLY1(3,1,msk) BFLY1(3,2,msk) BFLY1(3,3,msk)

#define STORE1(rs, i)                                                        \
    sdq[quarter][(rs) * 16 + rbase + (i)] = best_##rs##_##i;                 \
    siq[quarter][(rs) * 16 + rbase + (i)] = idx_##rs##_##i;

__global__ __launch_bounds__(256, 2) void vq_kernel(const float* __restrict__ x,
                                                    const char* __restrict__ wsb,
                                                    int* __restrict__ out) {
    __shared__ f4    xs4[ROWS][17];
    __shared__ float sEn[1024];
    __shared__ float sdq[4][64];
    __shared__ int   siq[4][64];

    const int tid = threadIdx.x;
    const int lane = tid & 63;
    const int quarter = __builtin_amdgcn_readfirstlane(tid >> 6);
    const int m_ = lane & 15;
    const int ko = (lane >> 4) * 8;
    const int n0 = blockIdx.x * ROWS;
    const int b = n0 >> 12;
    const int hw0 = n0 & (HW - 1);

    // stage e-norms
    const float* enp = (const float*)(wsb + 384 * 1024);
#pragma unroll
    for (int q = 0; q < 4; ++q) sEn[q * 256 + tid] = enp[q * 256 + tid];

    // stage x tile (fp32): wave q loads channels q*16..q*16+15 of all 64 rows
    {
        const float* g = x + ((size_t)b * D_DIM + quarter * 16) * HW + hw0 + lane;
        float v[16];
#pragma unroll
        for (int i = 0; i < 16; ++i) v[i] = g[(size_t)i * HW];
#pragma unroll
        for (int j = 0; j < 4; ++j)
            xs4[lane][quarter * 4 + j] = (f4){v[4*j], v[4*j+1], v[4*j+2], v[4*j+3]};
    }
    __syncthreads();

    // build A fragments of (-2x): 4 rowstripes x 2 ksteps x 3 levels
    s8v Ah00, Am00, Al00, Ah01, Am01, Al01;
    s8v Ah10, Am10, Al10, Ah11, Am11, Al11;
    s8v Ah20, Am20, Al20, Ah21, Am21, Al21;
    s8v Ah30, Am30, Al30, Ah31, Am31, Al31;
    BUILD_AS(0,0) BUILD_AS(0,1) BUILD_AS(1,0) BUILD_AS(1,1)
    BUILD_AS(2,0) BUILD_AS(2,1) BUILD_AS(3,0) BUILD_AS(3,1)

    f4 acc0 = (f4){0.f,0.f,0.f,0.f}, acc1 = (f4){0.f,0.f,0.f,0.f};
    f4 acc2 = (f4){0.f,0.f,0.f,0.f}, acc3 = (f4){0.f,0.f,0.f,0.f};
    float best_0_0=INF_, best_0_1=INF_, best_0_2=INF_, best_0_3=INF_;
    float best_1_0=INF_, best_1_1=INF_, best_1_2=INF_, best_1_3=INF_;
    float best_2_0=INF_, best_2_1=INF_, best_2_2=INF_, best_2_3=INF_;
    float best_3_0=INF_, best_3_1=INF_, best_3_2=INF_, best_3_3=INF_;
    int idx_0_0=0, idx_0_1=0, idx_0_2=0, idx_0_3=0;
    int idx_1_0=0, idx_1_1=0, idx_1_2=0, idx_1_3=0;
    int idx_2_0=0, idx_2_1=0, idx_2_2=0, idx_2_3=0;
    int idx_3_0=0, idx_3_1=0, idx_3_2=0, idx_3_3=0;

    // B double buffers
    s8v Bh0c, Bm0c, Bl0c, Bh1c, Bm1c, Bl1c;
    s8v Bh0n, Bm0n, Bl0n, Bh1n, Bm1n, Bl1n;

    const char* const bp0 = wsb + (size_t)quarter * 98304 + (size_t)lane * 16;
    const char* bp = bp0;
    LOADB(c, bp)            // tile t=0
    bp += 6144;

#pragma unroll 1
    for (int tt = 0; tt < 8; ++tt) {
        const int t0 = 2 * tt;
        DO_TILE(c, n, quarter * 16 + t0, bp)       // prefetch t0+1
        bp += 6144;
        const char* np = (tt == 7) ? bp0 : bp;     // wrap (discarded) on last
        DO_TILE(n, c, quarter * 16 + t0 + 1, np)   // prefetch t0+2
        bp += 6144;
    }

    // per-row argmin across the 16 cols held by this lane's 16-lane group
    BFLY_ALL(1) BFLY_ALL(2) BFLY_ALL(4) BFLY_ALL(8)

    if ((lane & 15) == 0) {
        const int rbase = (lane >> 4) * 4;
        STORE1(0,0) STORE1(0,1) STORE1(0,2) STORE1(0,3)
        STORE1(1,0) STORE1(1,1) STORE1(1,2) STORE1(1,3)
        STORE1(2,0) STORE1(2,1) STORE1(2,2) STORE1(2,3)
        STORE1(3,0) STORE1(3,1) STORE1(3,2) STORE1(3,3)
    }
    __syncthreads();

    // combine 4 K-quarters per row; lower quarter (lower k) wins ties
    if (tid < 64) {
        float bv = sdq[0][tid];
        int   bi = siq[0][tid];
#pragma unroll
        for (int q = 1; q < 4; ++q) {
            const float o = sdq[q][tid];
            const int  oi = siq[q][tid];
            if (o < bv) { bv = o; bi = oi; }
        }
        out[n0 + tid] = bi;
    }
}

extern "C" void kernel_launch(void* const* d_in, const int* in_sizes, int n_in,
                              void* d_out, int out_size, void* d_ws, size_t ws_size,
                              hipStream_t stream) {
    const float* x  = (const float*)d_in[0];   // [16,64,64,64] fp32
    const float* cb = (const float*)d_in[1];   // [1024,64] fp32
    char* wsb = (char*)d_ws;                   // 384KB packed cb + 4KB enorm
    int*  out = (int*)d_out;                   // 65536 int32 indices

    prep_kernel<<<dim3(400), dim3(64), 0, stream>>>(cb, wsb);
    vq_kernel<<<dim3(65536 / ROWS), dim3(256), 0, stream>>>(x, wsb, out);
}